// Round 9
// baseline (172.214 us; speedup 1.0000x reference)
//
#include <hip/hip_runtime.h>
#include <stdint.h>
#include <math.h>

// Problem constants
#define B_    2
#define T_    2048
#define C_    1024
#define H_    16
#define D_    64
#define MTOT  4096            // B*T
#define NQKV  3072            // 3*C
#define KDIM  1024            // C

#define LOG2E 1.4426950408889634f

typedef short short8 __attribute__((ext_vector_type(8)));   // 8 bf16 in 4 VGPRs
typedef float f32x4  __attribute__((ext_vector_type(4)));

__device__ __forceinline__ uint16_t f2b(float f) {
    union { float f; uint32_t u; } x; x.f = f;
    uint32_t u = x.u;
    return (uint16_t)((u + 0x7FFFu + ((u >> 16) & 1u)) >> 16);   // RNE
}
// fast pack of two floats -> two bf16 in one u32 (round-to-nearest, no tie-even)
__device__ __forceinline__ uint32_t packb2(float a, float b) {
    union { float f; uint32_t u; } x, y; x.f = a; y.f = b;
    return ((x.u + 0x8000u) >> 16) | ((y.u + 0x8000u) & 0xffff0000u);
}
__device__ __forceinline__ uint32_t packb2_rne(float a, float b) {
    return (uint32_t)f2b(a) | ((uint32_t)f2b(b) << 16);
}
__device__ __forceinline__ float fexp2(float x) {
#if __has_builtin(__builtin_amdgcn_exp2f)
    return __builtin_amdgcn_exp2f(x);
#else
    return exp2f(x);
#endif
}

// ---------------------------------------------------------------- cast (single launch: x, Wa, Wp-permute)
// One fp32 pass -> compact bf16 copies; GEMMs re-read panels 24-32x (R6 lesson:
// fusing the cast into the GEMM doubles FETCH_SIZE and loses ~23us).
#define N4X 1048576           // 4096*1024/4
#define N4W 786432            // 3072*1024/4
#define N4P 262144            // 1024*1024/4

__global__ __launch_bounds__(256) void cast_all(const float* __restrict__ x,
                                                const float* __restrict__ wa,
                                                const float* __restrict__ wp,
                                                uint16_t* __restrict__ xb,
                                                uint16_t* __restrict__ wab,
                                                uint16_t* __restrict__ wt) {
    int i = blockIdx.x * blockDim.x + threadIdx.x;
    if (i < N4X + N4W) {
        const float* src; uint16_t* dst; int j;
        if (i < N4X) { src = x; dst = xb; j = i; }
        else { src = wa; dst = wab; j = i - N4X; }
        float4 v = ((const float4*)src)[j];
        ushort4 o;
        o.x = f2b(v.x); o.y = f2b(v.y); o.z = f2b(v.z); o.w = f2b(v.w);
        ((ushort4*)dst)[j] = o;
    } else {
        int j = i - (N4X + N4W);              // over 1024*1024/4
        int j4 = (j & 255) * 4;
        int d  = j >> 8;
        int h = j4 >> 6, v = j4 & 63;
        float4 val = *(const float4*)(wp + h * 65536 + d * 64 + v);
        ushort4 o;
        o.x = f2b(val.x); o.y = f2b(val.y); o.z = f2b(val.z); o.w = f2b(val.w);
        *(ushort4*)(wt + d * 1024 + j4) = o;   // Wt[d][h*64+v]
    }
}

// ---------------------------------------------------------------- GEMM1a: Q/K columns (0..2047)
// SWAPPED MFMA operands: C'[qkvcol][t] — r-dim = 4 consecutive d => packed 8B [t][d] stores.
// BK=64, swizzled LDS, 2-deep A prefetch (R7 structure).
__global__ __launch_bounds__(256, 3) void gemm_qkv_qk(const uint16_t* __restrict__ A,   // x bf16 [4096][1024]
                                                      const uint16_t* __restrict__ Bw,  // Wa bf16 [3072][1024]
                                                      uint16_t* __restrict__ qkvb) {
    __shared__ __align__(16) uint16_t As[128 * 64];   // swizzled: (r,k) at r*64 + ((k/8)^(r&7))*8 + k%8
    __shared__ __align__(16) uint16_t Bs[128 * 64];

    int tid = threadIdx.x;
    int w = tid >> 6, lane = tid & 63;
    int qd = lane >> 4, ln = lane & 15;
    int lnx = ln & 7;
    int rowBase = blockIdx.y * 128;
    int colBase = blockIdx.x * 128;       // 0..1920 (Q/K thirds)
    int mw = (w >> 1) * 64, nw = (w & 1) * 64;

    int srow = tid >> 3;
    int pchunk = tid & 7;
    int gchunk = pchunk ^ (srow & 7);

    const uint16_t* ga = A  + (size_t)(rowBase + srow) * KDIM + gchunk * 8;
    const uint16_t* gb = Bw + (size_t)(colBase + srow) * KDIM + gchunk * 8;
    uint16_t* la = &As[srow * 64 + pchunk * 8];
    uint16_t* lb = &Bs[srow * 64 + pchunk * 8];

    short8 paE[4], paO[4], pb[4];
#pragma unroll
    for (int m = 0; m < 4; m++) {
        paE[m] = *(const short8*)(ga + (size_t)m * 32 * KDIM);
        paO[m] = *(const short8*)(ga + 64 + (size_t)m * 32 * KDIM);
        pb[m]  = *(const short8*)(gb + (size_t)m * 32 * KDIM);
    }

    f32x4 acc[4][4] = {};   // [x-tile i][wa-tile j], C' = (x@Wa^T)^T placement

#define QSTEP(PAC, S)                                                            \
    {                                                                            \
        _Pragma("unroll")                                                        \
        for (int m = 0; m < 4; m++) {                                            \
            *(short8*)(la + m * 32 * 64) = PAC[m];                               \
            *(short8*)(lb + m * 32 * 64) = pb[m];                                \
        }                                                                        \
        __syncthreads();                                                         \
        if ((S) + 1 < 16) {                                                      \
            int kb_ = ((S) + 1) * 64;                                            \
            _Pragma("unroll")                                                    \
            for (int m = 0; m < 4; m++)                                          \
                pb[m] = *(const short8*)(gb + kb_ + (size_t)m * 32 * KDIM);      \
        }                                                                        \
        if ((S) + 2 < 16) {                                                      \
            int ka_ = ((S) + 2) * 64;                                            \
            _Pragma("unroll")                                                    \
            for (int m = 0; m < 4; m++)                                          \
                PAC[m] = *(const short8*)(ga + ka_ + (size_t)m * 32 * KDIM);     \
        }                                                                        \
        _Pragma("unroll")                                                        \
        for (int ks = 0; ks < 2; ks++) {                                         \
            int p = (ks * 4 + qd) ^ lnx;                                         \
            short8 a_[4], b_[4];                                                 \
            _Pragma("unroll")                                                    \
            for (int i = 0; i < 4; i++) {                                        \
                a_[i] = *(const short8*)&As[(mw + i * 16 + ln) * 64 + p * 8];    \
                b_[i] = *(const short8*)&Bs[(nw + i * 16 + ln) * 64 + p * 8];    \
            }                                                                    \
            _Pragma("unroll")                                                    \
            for (int i = 0; i < 4; i++)                                          \
                _Pragma("unroll")                                                \
                for (int j = 0; j < 4; j++)                                      \
                    acc[i][j] = __builtin_amdgcn_mfma_f32_16x16x32_bf16(b_[j], a_[i], acc[i][j], 0, 0, 0); \
        }                                                                        \
        __syncthreads();                                                         \
    }

    for (int sp = 0; sp < 8; sp++) {
        QSTEP(paE, 2 * sp);
        QSTEP(paO, 2 * sp + 1);
    }
#undef QSTEP

    // epilogue: which wave-uniform (colBase+nw is 64-aligned; thirds 1024-aligned)
    int which = (colBase + nw) >> 10;          // 0 (Q) or 1 (K)
    float sc = (which == 0) ? LOG2E : 1.0f;    // Q pre-scaled so attn uses exp2
#pragma unroll
    for (int i = 0; i < 4; i++) {
#pragma unroll
        for (int j = 0; j < 4; j++) {
            int mcol = colBase + nw + j * 16 + qd * 4;   // qkv col for r=0
            int rem = mcol & 1023;
            int h = rem >> 6, d0 = rem & 63;             // d0 4-aligned, head-uniform over r
            int grow = rowBase + mw + i * 16 + ln;       // t index
            int bb = grow >> 11, tt = grow & 2047;
            uint2 pk2;
            pk2.x = packb2_rne(acc[i][j][0] * sc, acc[i][j][1] * sc);
            pk2.y = packb2_rne(acc[i][j][2] * sc, acc[i][j][3] * sc);
            *(uint2*)&qkvb[(size_t)which * 4194304 + ((size_t)(bb * H_ + h) * T_ + tt) * D_ + d0] = pk2;
        }
    }
}

// ---------------------------------------------------------------- GEMM1b: V columns (2048..3071) -> V^T [bh][d][t]
// Normal operand order: r-dim = 4 consecutive t => packed 8B [d][t] stores (R7 path).
__global__ __launch_bounds__(256, 3) void gemm_qkv_v(const uint16_t* __restrict__ A,
                                                     const uint16_t* __restrict__ Bw,
                                                     uint16_t* __restrict__ qkvb) {
    __shared__ __align__(16) uint16_t As[128 * 64];
    __shared__ __align__(16) uint16_t Bs[128 * 64];

    int tid = threadIdx.x;
    int w = tid >> 6, lane = tid & 63;
    int qd = lane >> 4, ln = lane & 15;
    int lnx = ln & 7;
    int rowBase = blockIdx.y * 128;
    int colBase = 2048 + blockIdx.x * 128;
    int mw = (w >> 1) * 64, nw = (w & 1) * 64;

    int srow = tid >> 3;
    int pchunk = tid & 7;
    int gchunk = pchunk ^ (srow & 7);

    const uint16_t* ga = A  + (size_t)(rowBase + srow) * KDIM + gchunk * 8;
    const uint16_t* gb = Bw + (size_t)(colBase + srow) * KDIM + gchunk * 8;
    uint16_t* la = &As[srow * 64 + pchunk * 8];
    uint16_t* lb = &Bs[srow * 64 + pchunk * 8];

    short8 paE[4], paO[4], pb[4];
#pragma unroll
    for (int m = 0; m < 4; m++) {
        paE[m] = *(const short8*)(ga + (size_t)m * 32 * KDIM);
        paO[m] = *(const short8*)(ga + 64 + (size_t)m * 32 * KDIM);
        pb[m]  = *(const short8*)(gb + (size_t)m * 32 * KDIM);
    }

    f32x4 acc[4][4] = {};

#define VSTEP(PAC, S)                                                            \
    {                                                                            \
        _Pragma("unroll")                                                        \
        for (int m = 0; m < 4; m++) {                                            \
            *(short8*)(la + m * 32 * 64) = PAC[m];                               \
            *(short8*)(lb + m * 32 * 64) = pb[m];                                \
        }                                                                        \
        __syncthreads();                                                         \
        if ((S) + 1 < 16) {                                                      \
            int kb_ = ((S) + 1) * 64;                                            \
            _Pragma("unroll")                                                    \
            for (int m = 0; m < 4; m++)                                          \
                pb[m] = *(const short8*)(gb + kb_ + (size_t)m * 32 * KDIM);      \
        }                                                                        \
        if ((S) + 2 < 16) {                                                      \
            int ka_ = ((S) + 2) * 64;                                            \
            _Pragma("unroll")                                                    \
            for (int m = 0; m < 4; m++)                                          \
                PAC[m] = *(const short8*)(ga + ka_ + (size_t)m * 32 * KDIM);     \
        }                                                                        \
        _Pragma("unroll")                                                        \
        for (int ks = 0; ks < 2; ks++) {                                         \
            int p = (ks * 4 + qd) ^ lnx;                                         \
            short8 a_[4], b_[4];                                                 \
            _Pragma("unroll")                                                    \
            for (int i = 0; i < 4; i++) {                                        \
                a_[i] = *(const short8*)&As[(mw + i * 16 + ln) * 64 + p * 8];    \
                b_[i] = *(const short8*)&Bs[(nw + i * 16 + ln) * 64 + p * 8];    \
            }                                                                    \
            _Pragma("unroll")                                                    \
            for (int i = 0; i < 4; i++)                                          \
                _Pragma("unroll")                                                \
                for (int j = 0; j < 4; j++)                                      \
                    acc[i][j] = __builtin_amdgcn_mfma_f32_16x16x32_bf16(a_[i], b_[j], acc[i][j], 0, 0, 0); \
        }                                                                        \
        __syncthreads();                                                         \
    }

    for (int sp = 0; sp < 8; sp++) {
        VSTEP(paE, 2 * sp);
        VSTEP(paO, 2 * sp + 1);
    }
#undef VSTEP

#pragma unroll
    for (int i = 0; i < 4; i++) {
#pragma unroll
        for (int j = 0; j < 4; j++) {
            int gcol = colBase + nw + j * 16 + ln;
            int rem = gcol & 1023;
            int h = rem >> 6, d = rem & 63;
            // V^T: 4 consecutive t per thread -> one 8B packed store (t0 4-aligned)
            int t0 = rowBase + mw + i * 16 + qd * 4;
            int bb = t0 >> 11, t = t0 & 2047;
            uint2 pk2;
            pk2.x = packb2_rne(acc[i][j][0], acc[i][j][1]);
            pk2.y = packb2_rne(acc[i][j][2], acc[i][j][3]);
            *(uint2*)&qkvb[(size_t)2 * 4194304 + (((size_t)(bb * H_ + h) * D_) + d) * T_ + t] = pk2;
        }
    }
}

// ---------------------------------------------------------------- attention
// Per-CU-unique-line bound => share K/V tiles across waves via LDS.
// Block = 8 waves (512 thr), handles q-groups j and 15-j (128 q-rows each) in ONE
// fused kt loop (nt = 32-2j staging iterations, 34 strip-iterations — balanced).
// Wave w owns q-rows [qg*128+w*16, +16) exclusively: no split-K, no combine.
// K/V tiles staged once per block per kt (swizzled, reg-prefetch, dbuf, 1 barrier/kt).
// S^T = K Q^T; p = exp2(s) (Q pre-scaled by log2e); P^T via per-wave LDS; O^T = Vt P^T.

#define STRIP(QS, BQ, OT, LSUM)                                              \
    if (kt * 64 <= (QS) + 15) {                                              \
        bool needm = (kt * 64 + 63 > (QS));                                  \
        f32x4 stt[4];                                                        \
        __builtin_amdgcn_s_setprio(1);                                       \
        _Pragma("unroll")                                                    \
        for (int it = 0; it < 4; it++) {                                     \
            f32x4 z = {};                                                    \
            z = __builtin_amdgcn_mfma_f32_16x16x32_bf16(ak[it][0], (BQ)[0], z, 0, 0, 0); \
            z = __builtin_amdgcn_mfma_f32_16x16x32_bf16(ak[it][1], (BQ)[1], z, 0, 0, 0); \
            stt[it] = z;                                                     \
        }                                                                    \
        __builtin_amdgcn_s_setprio(0);                                       \
        if (needm) {                                                         \
            _Pragma("unroll")                                                \
            for (int it = 0; it < 4; it++)                                   \
                _Pragma("unroll")                                            \
                for (int r = 0; r < 4; r++) {                                \
                    int t = kt * 64 + it * 16 + qd * 4 + r;                  \
                    if (t > (QS) + ln) stt[it][r] = -1.0e30f;                \
                }                                                            \
        }                                                                    \
        _Pragma("unroll")                                                    \
        for (int it = 0; it < 4; it++) {                                     \
            float p0 = fexp2(stt[it][0]);                                    \
            float p1 = fexp2(stt[it][1]);                                    \
            float p2 = fexp2(stt[it][2]);                                    \
            float p3 = fexp2(stt[it][3]);                                    \
            (LSUM) += (p0 + p1) + (p2 + p3);                                 \
            uint2 pk2;                                                       \
            pk2.x = packb2(p0, p1);                                          \
            pk2.y = packb2(p2, p3);                                          \
            *(uint2*)&Pl[w][ln][it * 16 + qd * 4] = pk2;                     \
        }                                                                    \
        short8 bp0 = *(const short8*)&Pl[w][ln][qd * 8];                     \
        short8 bp1 = *(const short8*)&Pl[w][ln][32 + qd * 8];                \
        __builtin_amdgcn_s_setprio(1);                                       \
        _Pragma("unroll")                                                    \
        for (int id = 0; id < 4; id++) {                                     \
            (OT)[id] = __builtin_amdgcn_mfma_f32_16x16x32_bf16(av[id][0], bp0, (OT)[id], 0, 0, 0); \
            (OT)[id] = __builtin_amdgcn_mfma_f32_16x16x32_bf16(av[id][1], bp1, (OT)[id], 0, 0, 0); \
        }                                                                    \
        __builtin_amdgcn_s_setprio(0);                                       \
    }

#define EPI(QS, OT, LSUM)                                                    \
    {                                                                        \
        float ssum = (LSUM);                                                 \
        ssum += __shfl_xor(ssum, 16);                                        \
        ssum += __shfl_xor(ssum, 32);                                        \
        float rl = 1.0f / ssum;                                              \
        int q = (QS) + ln;                                                   \
        _Pragma("unroll")                                                    \
        for (int id = 0; id < 4; id++) {                                     \
            float v0 = (OT)[id][0] * rl;                                     \
            float v1 = (OT)[id][1] * rl;                                     \
            float v2 = (OT)[id][2] * rl;                                     \
            float v3 = (OT)[id][3] * rl;                                     \
            uint2 pk2;                                                       \
            pk2.x = packb2_rne(v0, v1);                                      \
            pk2.y = packb2_rne(v2, v3);                                      \
            *(uint2*)&oc[(size_t)(b * T_ + q) * C_ + h * 64 + id * 16 + qd * 4] = pk2; \
        }                                                                    \
    }

__global__ __launch_bounds__(512, 2) void attn(const uint16_t* __restrict__ qkvb,
                                               uint16_t* __restrict__ oc) {         // O_concat bf16 [4096][1024]
    __shared__ __align__(16) uint16_t Ks[2][64 * 64];   // swizzled: (t, chunk c) at t*64 + (c^(t&7))*8
    __shared__ __align__(16) uint16_t Vs[2][64 * 64];   // swizzled: (d, chunk c) likewise
    __shared__ __align__(16) uint16_t Pl[8][16][72];    // per-wave P^T strip [q16][t64+pad]

    int tid = threadIdx.x;
    int w = tid >> 6, lane = tid & 63;
    int qd = lane >> 4, ln = lane & 15;
    int lnx = ln & 7;
    int bid = blockIdx.x;
    int j = bid >> 5;                  // 0..7 pair index
    int bh = bid & 31;                 // bid%8 == bh%8 → bh→XCD L2 affinity
    int b = bh >> 4, h = bh & 15;

    const uint16_t* Q0 = qkvb + (size_t)bh * T_ * D_;
    const uint16_t* K  = Q0 + 4194304;
    const uint16_t* Vt = qkvb + (size_t)2 * 4194304 + (size_t)bh * D_ * T_;   // [64 d][2048 t]

    int qsA = j * 128 + w * 16;        // light q-group
    int qsB = (15 - j) * 128 + w * 16; // heavy q-group
    int nt  = 32 - 2 * j;              // k-tiles needed by the heavy group

    // persistent Q fragments (B-operand, n=q16, k=d)
    short8 bqA[2], bqB[2];
#pragma unroll
    for (int ks = 0; ks < 2; ks++) {
        bqA[ks] = *(const short8*)(Q0 + (size_t)(qsA + ln) * D_ + ks * 32 + qd * 8);
        bqB[ks] = *(const short8*)(Q0 + (size_t)(qsB + ln) * D_ + ks * 32 + qd * 8);
    }

    // staging: 512 threads cover 64 rows x 8 chunks of 16B, chunk XOR-swizzled
    int srow = tid >> 3;               // 0..63
    int pch = tid & 7;
    int gch = pch ^ (srow & 7);
    const uint16_t* gk = K  + (size_t)srow * D_ + gch * 8;   // K row = kt*64+srow
    const uint16_t* gv = Vt + (size_t)srow * T_ + gch * 8;   // V^T row d = srow, col = kt*64+..
    int lofs = srow * 64 + pch * 8;

    short8 pk = *(const short8*)gk;    // tile kt=0 prefetch
    short8 pv = *(const short8*)gv;

    f32x4 otA[4] = {}, otB[4] = {};    // O^T [d-tile id][q16], per strip
    float lA = 0.f, lB = 0.f;

    int c = 0;
    for (int kt = 0; kt < nt; kt++) {
        *(short8*)&Ks[c][lofs] = pk;
        *(short8*)&Vs[c][lofs] = pv;
        __syncthreads();
        if (kt + 1 < nt) {
            pk = *(const short8*)(gk + (size_t)(kt + 1) * 64 * D_);
            pv = *(const short8*)(gv + (size_t)(kt + 1) * 64);
        }
        // shared K/V fragments for both strips (A-operands)
        short8 ak[4][2], av[4][2];
#pragma unroll
        for (int ks = 0; ks < 2; ks++) {
            int p8 = ((ks * 4 + qd) ^ lnx) * 8;
#pragma unroll
            for (int it = 0; it < 4; it++) {
                ak[it][ks] = *(const short8*)&Ks[c][(it * 16 + ln) * 64 + p8];
                av[it][ks] = *(const short8*)&Vs[c][(it * 16 + ln) * 64 + p8];
            }
        }
        STRIP(qsA, bqA, otA, lA);
        STRIP(qsB, bqB, otB, lB);
        c ^= 1;
    }

    EPI(qsA, otA, lA);
    EPI(qsB, otB, lB);
}

// ---------------------------------------------------------------- GEMM2 (tile 128x64, BK=64, swizzled, 2-deep A prefetch)
__global__ __launch_bounds__(256, 3) void gemm_out(const uint16_t* __restrict__ A,   // O_concat bf16 [4096][1024]
                                                   const uint16_t* __restrict__ Bw,  // Wt bf16 [1024][1024]
                                                   float* __restrict__ out) {        // [4096][1024] fp32
    __shared__ __align__(16) uint16_t As[128 * 64];
    __shared__ __align__(16) uint16_t Bs[64 * 64];

    int tid = threadIdx.x;
    int w = tid >> 6, lane = tid & 63;
    int qd = lane >> 4, ln = lane & 15;
    int lnx = ln & 7;
    int rowBase = blockIdx.y * 128;
    int colBase = blockIdx.x * 64;
    int mw = (w >> 1) * 64, nw = (w & 1) * 32;

    int srow = tid >> 3;
    int pchunk = tid & 7;
    int gchunk = pchunk ^ (srow & 7);

    const uint16_t* ga = A  + (size_t)(rowBase + srow) * KDIM + gchunk * 8;
    const uint16_t* gb = Bw + (size_t)(colBase + srow) * KDIM + gchunk * 8;
    uint16_t* la = &As[srow * 64 + pchunk * 8];
    uint16_t* lb = &Bs[srow * 64 + pchunk * 8];

    short8 paE[4], paO[4], pb[2];
#pragma unroll
    for (int m = 0; m < 4; m++) {
        paE[m] = *(const short8*)(ga + (size_t)m * 32 * KDIM);
        paO[m] = *(const short8*)(ga + 64 + (size_t)m * 32 * KDIM);
    }
#pragma unroll
    for (int m = 0; m < 2; m++)
        pb[m] = *(const short8*)(gb + (size_t)m * 32 * KDIM);

    f32x4 acc[4][2] = {};

#define OSTEP(PAC, S)                                                            \
    {                                                                            \
        _Pragma("unroll")                                                        \
        for (int m = 0; m < 4; m++)                                              \
            *(short8*)(la + m * 32 * 64) = PAC[m];                               \
        _Pragma("unroll")                                                        \
        for (int m = 0; m < 2; m++)                                              \
            *(short8*)(lb + m * 32 * 64) = pb[m];                                \
        __syncthreads();                                                         \
        if ((S) + 1 < 16) {                                                      \
            int kb_ = ((S) + 1) * 64;                                            \
            _Pragma("unroll")                                                    \
            for (int m = 0; m < 2; m++)                                          \
                pb[m] = *(const short8*)(gb + kb_ + (size_t)m * 32 * KDIM);      \
        }                                                                        \
        if ((S) + 2 < 16) {                                                      \
            int ka_ = ((S) + 2) * 64;                                            \
            _Pragma("unroll")                                                    \
            for (int m = 0; m < 4; m++)                                          \
                PAC[m] = *(const short8*)(ga + ka_ + (size_t)m * 32 * KDIM);     \
        }                                                                        \
        _Pragma("unroll")                                                        \
        for (int ks = 0; ks < 2; ks++) {                                         \
            int p = (ks * 4 + qd) ^ lnx;                                         \
            short8 a_[4], b_[2];                                                 \
            _Pragma("unroll")                                                    \
            for (int i = 0; i < 4; i++)                                          \
                a_[i] = *(const short8*)&As[(mw + i * 16 + ln) * 64 + p * 8];    \
            _Pragma("unroll")                                                    \
            for (int j = 0; j < 2; j++)                                          \
                b_[j] = *(const short8*)&Bs[(nw + j * 16 + ln) * 64 + p * 8];    \
            _Pragma("unroll")                                                    \
            for (int i = 0; i < 4; i++)                                          \
                _Pragma("unroll")                                                \
                for (int j = 0; j < 2; j++)                                      \
                    acc[i][j] = __builtin_amdgcn_mfma_f32_16x16x32_bf16(a_[i], b_[j], acc[i][j], 0, 0, 0); \
        }                                                                        \
        __syncthreads();                                                         \
    }

    for (int sp = 0; sp < 8; sp++) {
        OSTEP(paE, 2 * sp);
        OSTEP(paO, 2 * sp + 1);
    }
#undef OSTEP

#pragma unroll
    for (int i = 0; i < 4; i++)
#pragma unroll
        for (int j = 0; j < 2; j++)
#pragma unroll
            for (int r = 0; r < 4; r++) {
                int grow = rowBase + mw + i * 16 + qd * 4 + r;
                int gcol = colBase + nw + j * 16 + ln;
                out[(size_t)grow * 1024 + gcol] = acc[i][j][r];
            }
}

// ---------------------------------------------------------------- launch
extern "C" void kernel_launch(void* const* d_in, const int* in_sizes, int n_in,
                              void* d_out, int out_size, void* d_ws, size_t ws_size,
                              hipStream_t stream) {
    const float* x  = (const float*)d_in[0];
    const float* Wa = (const float*)d_in[1];
    const float* Wp = (const float*)d_in[2];
    float* out = (float*)d_out;

    uint16_t* ws   = (uint16_t*)d_ws;
    uint16_t* xb   = ws;                       // 4096*1024
    uint16_t* Wab  = xb + 4194304;             // 3072*1024
    uint16_t* Wtb  = Wab + 3145728;            // 1024*1024
    uint16_t* qkvb = Wtb + 1048576;            // Q,K: [bh][t][d] (Q pre-scaled by log2e); V: [bh][d][t]
    uint16_t* ob   = qkvb + (size_t)3 * 4194304; // 4096*1024

    cast_all<<<8192, 256, 0, stream>>>(x, Wa, Wp, xb, Wab, Wtb);
    gemm_qkv_qk<<<dim3(16, 32), 256, 0, stream>>>(xb, Wab, qkvb);
    gemm_qkv_v<<<dim3(8, 32), 256, 0, stream>>>(xb, Wab, qkvb);
    attn<<<256, 512, 0, stream>>>(qkvb, ob);
    gemm_out<<<dim3(16, 32), 256, 0, stream>>>(ob, Wtb, out);
}

// Round 10
// 163.361 us; speedup vs baseline: 1.0542x; 1.0542x over previous
//
#include <hip/hip_runtime.h>
#include <stdint.h>
#include <math.h>

// Problem constants
#define B_    2
#define T_    2048
#define C_    1024
#define H_    16
#define D_    64
#define MTOT  4096            // B*T
#define NQKV  3072            // 3*C
#define KDIM  1024            // C

#define LOG2E 1.4426950408889634f

typedef short short8 __attribute__((ext_vector_type(8)));   // 8 bf16 in 4 VGPRs
typedef float f32x4  __attribute__((ext_vector_type(4)));

__device__ __forceinline__ uint16_t f2b(float f) {
    union { float f; uint32_t u; } x; x.f = f;
    uint32_t u = x.u;
    return (uint16_t)((u + 0x7FFFu + ((u >> 16) & 1u)) >> 16);   // RNE
}
// fast pack of two floats -> two bf16 in one u32 (round-to-nearest, no tie-even)
__device__ __forceinline__ uint32_t packb2(float a, float b) {
    union { float f; uint32_t u; } x, y; x.f = a; y.f = b;
    return ((x.u + 0x8000u) >> 16) | ((y.u + 0x8000u) & 0xffff0000u);
}
__device__ __forceinline__ uint32_t packb2_rne(float a, float b) {
    return (uint32_t)f2b(a) | ((uint32_t)f2b(b) << 16);
}
__device__ __forceinline__ float fexp2(float x) {
#if __has_builtin(__builtin_amdgcn_exp2f)
    return __builtin_amdgcn_exp2f(x);
#else
    return exp2f(x);
#endif
}

// ---------------------------------------------------------------- casts (merged)
// One fp32 pass -> compact bf16 copies; the GEMMs re-read panels 24-32x, so the
// bf16 intermediates halve all L2->L1 re-read traffic (R6 lesson: fusing the cast
// into the GEMM doubles FETCH_SIZE and loses ~23us).
__global__ __launch_bounds__(256) void cast_all(const float* __restrict__ x,
                                                const float* __restrict__ wa,
                                                uint16_t* __restrict__ xb,
                                                uint16_t* __restrict__ wab,
                                                int n4x, int n4w) {
    int i = blockIdx.x * blockDim.x + threadIdx.x;
    const float* src; uint16_t* dst; int j;
    if (i < n4x) { src = x; dst = xb; j = i; }
    else { j = i - n4x; if (j >= n4w) return; src = wa; dst = wab; }
    float4 v = ((const float4*)src)[j];
    ushort4 o;
    o.x = f2b(v.x); o.y = f2b(v.y); o.z = f2b(v.z); o.w = f2b(v.w);
    ((ushort4*)dst)[j] = o;
}

// Wt[d][j=h*64+v] = Wp_flat[h*65536 + d*64 + v], bf16
__global__ __launch_bounds__(256) void cast_wp(const float* __restrict__ wp,
                                               uint16_t* __restrict__ wt) {
    int i = blockIdx.x * blockDim.x + threadIdx.x;   // over 1024*1024/4
    int j4 = (i & 255) * 4;
    int d  = i >> 8;
    int h = j4 >> 6, v = j4 & 63;
    float4 val = *(const float4*)(wp + h * 65536 + d * 64 + v);
    ushort4 o;
    o.x = f2b(val.x); o.y = f2b(val.y); o.z = f2b(val.z); o.w = f2b(val.w);
    *(ushort4*)(wt + d * 1024 + j4) = o;
}

// ---------------------------------------------------------------- GEMM1 (BK=64, swizzled LDS, 2-deep A prefetch)
// qkv = x @ Wa^T; scatter: Q (scaled by log2e), K -> [B][H][T][D]; V -> [B][H][D][T]
// Per-CU L2->L1 line-BW bound: deeper register prefetch (A 2 tiles ahead) keeps more
// lines in flight per wave. Even/odd named register sets keep indexing static (rule #20).
__global__ __launch_bounds__(256, 3) void gemm_qkv(const uint16_t* __restrict__ A,   // x bf16 [4096][1024]
                                                   const uint16_t* __restrict__ Bw,  // Wa bf16 [3072][1024]
                                                   uint16_t* __restrict__ qkvb) {
    __shared__ __align__(16) uint16_t As[128 * 64];   // swizzled: (r,k) at r*64 + ((k/8)^(r&7))*8 + k%8
    __shared__ __align__(16) uint16_t Bs[128 * 64];

    int tid = threadIdx.x;
    int w = tid >> 6, lane = tid & 63;
    int qd = lane >> 4, ln = lane & 15;
    int lnx = ln & 7;
    int rowBase = blockIdx.y * 128;
    int colBase = blockIdx.x * 128;
    int mw = (w >> 1) * 64, nw = (w & 1) * 64;

    int srow = tid >> 3;                 // 0..31
    int pchunk = tid & 7;                // physical chunk
    int gchunk = pchunk ^ (srow & 7);    // logical k-chunk for that slot

    const uint16_t* ga = A  + (size_t)(rowBase + srow) * KDIM + gchunk * 8;
    const uint16_t* gb = Bw + (size_t)(colBase + srow) * KDIM + gchunk * 8;
    uint16_t* la = &As[srow * 64 + pchunk * 8];
    uint16_t* lb = &Bs[srow * 64 + pchunk * 8];

    short8 paE[4], paO[4], pb[4];
#pragma unroll
    for (int m = 0; m < 4; m++) {
        paE[m] = *(const short8*)(ga + (size_t)m * 32 * KDIM);
        paO[m] = *(const short8*)(ga + 64 + (size_t)m * 32 * KDIM);
        pb[m]  = *(const short8*)(gb + (size_t)m * 32 * KDIM);
    }

    f32x4 acc[4][4] = {};

#define QSTEP(PAC, S)                                                            \
    {                                                                            \
        _Pragma("unroll")                                                        \
        for (int m = 0; m < 4; m++) {                                            \
            *(short8*)(la + m * 32 * 64) = PAC[m];                               \
            *(short8*)(lb + m * 32 * 64) = pb[m];                                \
        }                                                                        \
        __syncthreads();                                                         \
        if ((S) + 1 < 16) {                                                      \
            int kb_ = ((S) + 1) * 64;                                            \
            _Pragma("unroll")                                                    \
            for (int m = 0; m < 4; m++)                                          \
                pb[m] = *(const short8*)(gb + kb_ + (size_t)m * 32 * KDIM);      \
        }                                                                        \
        if ((S) + 2 < 16) {                                                      \
            int ka_ = ((S) + 2) * 64;                                            \
            _Pragma("unroll")                                                    \
            for (int m = 0; m < 4; m++)                                          \
                PAC[m] = *(const short8*)(ga + ka_ + (size_t)m * 32 * KDIM);     \
        }                                                                        \
        _Pragma("unroll")                                                        \
        for (int ks = 0; ks < 2; ks++) {                                         \
            int p = (ks * 4 + qd) ^ lnx;                                         \
            short8 a_[4], b_[4];                                                 \
            _Pragma("unroll")                                                    \
            for (int i = 0; i < 4; i++) {                                        \
                a_[i] = *(const short8*)&As[(mw + i * 16 + ln) * 64 + p * 8];    \
                b_[i] = *(const short8*)&Bs[(nw + i * 16 + ln) * 64 + p * 8];    \
            }                                                                    \
            _Pragma("unroll")                                                    \
            for (int i = 0; i < 4; i++)                                          \
                _Pragma("unroll")                                                \
                for (int j = 0; j < 4; j++)                                      \
                    acc[i][j] = __builtin_amdgcn_mfma_f32_16x16x32_bf16(a_[i], b_[j], acc[i][j], 0, 0, 0); \
        }                                                                        \
        __syncthreads();                                                         \
    }

    for (int sp = 0; sp < 8; sp++) {
        QSTEP(paE, 2 * sp);
        QSTEP(paO, 2 * sp + 1);
    }
#undef QSTEP

#pragma unroll
    for (int i = 0; i < 4; i++) {
#pragma unroll
        for (int j = 0; j < 4; j++) {
            int gcol = colBase + nw + j * 16 + ln;
            int which = gcol >> 10;
            int rem = gcol & 1023;
            int h = rem >> 6, d = rem & 63;
            if (which == 2) {
                // V^T: 4 consecutive t per thread -> one 8B packed store (t0 4-aligned)
                int t0 = rowBase + mw + i * 16 + qd * 4;
                int bb = t0 >> 11, t = t0 & 2047;
                uint2 pk2;
                pk2.x = packb2_rne(acc[i][j][0], acc[i][j][1]);
                pk2.y = packb2_rne(acc[i][j][2], acc[i][j][3]);
                *(uint2*)&qkvb[(size_t)2 * 4194304 + (((size_t)(bb * H_ + h) * D_) + d) * T_ + t] = pk2;
            } else {
                float sc = (which == 0) ? LOG2E : 1.0f;   // Q pre-scaled so attn uses exp2
#pragma unroll
                for (int r = 0; r < 4; r++) {
                    int grow = rowBase + mw + i * 16 + qd * 4 + r;
                    int bb = grow >> 11, t = grow & 2047;
                    uint16_t val = f2b(acc[i][j][r] * sc);
                    qkvb[(size_t)which * 4194304 + (((size_t)(bb * H_ + h) * T_) + t) * D_ + d] = val;
                }
            }
        }
    }
}

// ---------------------------------------------------------------- attention
// Per-CU-unique-line bound => share K/V tiles across waves via LDS.
// Block = 8 waves (512 thr), handles q-groups j and 15-j (128 q-rows each) in ONE
// fused kt loop (nt = 32-2j staging iterations, 34 strip-iterations — balanced).
// Wave w owns q-rows [qg*128+w*16, +16) exclusively: no split-K, no combine.
// K/V tiles staged once per block per kt (swizzled, reg-prefetch, dbuf, 1 barrier/kt).
// S^T = K Q^T; p = exp2(s) (Q pre-scaled by log2e); P^T via per-wave LDS; O^T = Vt P^T.

#define STRIP(QS, BQ, OT, LSUM)                                              \
    if (kt * 64 <= (QS) + 15) {                                              \
        bool needm = (kt * 64 + 63 > (QS));                                  \
        f32x4 stt[4];                                                        \
        __builtin_amdgcn_s_setprio(1);                                       \
        _Pragma("unroll")                                                    \
        for (int it = 0; it < 4; it++) {                                     \
            f32x4 z = {};                                                    \
            z = __builtin_amdgcn_mfma_f32_16x16x32_bf16(ak[it][0], (BQ)[0], z, 0, 0, 0); \
            z = __builtin_amdgcn_mfma_f32_16x16x32_bf16(ak[it][1], (BQ)[1], z, 0, 0, 0); \
            stt[it] = z;                                                     \
        }                                                                    \
        __builtin_amdgcn_s_setprio(0);                                       \
        if (needm) {                                                         \
            _Pragma("unroll")                                                \
            for (int it = 0; it < 4; it++)                                   \
                _Pragma("unroll")                                            \
                for (int r = 0; r < 4; r++) {                                \
                    int t = kt * 64 + it * 16 + qd * 4 + r;                  \
                    if (t > (QS) + ln) stt[it][r] = -1.0e30f;                \
                }                                                            \
        }                                                                    \
        _Pragma("unroll")                                                    \
        for (int it = 0; it < 4; it++) {                                     \
            float p0 = fexp2(stt[it][0]);                                    \
            float p1 = fexp2(stt[it][1]);                                    \
            float p2 = fexp2(stt[it][2]);                                    \
            float p3 = fexp2(stt[it][3]);                                    \
            (LSUM) += (p0 + p1) + (p2 + p3);                                 \
            uint2 pk2;                                                       \
            pk2.x = packb2(p0, p1);                                          \
            pk2.y = packb2(p2, p3);                                          \
            *(uint2*)&Pl[w][ln][it * 16 + qd * 4] = pk2;                     \
        }                                                                    \
        short8 bp0 = *(const short8*)&Pl[w][ln][qd * 8];                     \
        short8 bp1 = *(const short8*)&Pl[w][ln][32 + qd * 8];                \
        __builtin_amdgcn_s_setprio(1);                                       \
        _Pragma("unroll")                                                    \
        for (int id = 0; id < 4; id++) {                                     \
            (OT)[id] = __builtin_amdgcn_mfma_f32_16x16x32_bf16(av[id][0], bp0, (OT)[id], 0, 0, 0); \
            (OT)[id] = __builtin_amdgcn_mfma_f32_16x16x32_bf16(av[id][1], bp1, (OT)[id], 0, 0, 0); \
        }                                                                    \
        __builtin_amdgcn_s_setprio(0);                                       \
    }

#define EPI(QS, OT, LSUM)                                                    \
    {                                                                        \
        float ssum = (LSUM);                                                 \
        ssum += __shfl_xor(ssum, 16);                                        \
        ssum += __shfl_xor(ssum, 32);                                        \
        float rl = 1.0f / ssum;                                              \
        int q = (QS) + ln;                                                   \
        _Pragma("unroll")                                                    \
        for (int id = 0; id < 4; id++) {                                     \
            float v0 = (OT)[id][0] * rl;                                     \
            float v1 = (OT)[id][1] * rl;                                     \
            float v2 = (OT)[id][2] * rl;                                     \
            float v3 = (OT)[id][3] * rl;                                     \
            uint2 pk2;                                                       \
            pk2.x = packb2_rne(v0, v1);                                      \
            pk2.y = packb2_rne(v2, v3);                                      \
            *(uint2*)&oc[(size_t)(b * T_ + q) * C_ + h * 64 + id * 16 + qd * 4] = pk2; \
        }                                                                    \
    }

__global__ __launch_bounds__(512, 2) void attn(const uint16_t* __restrict__ qkvb,
                                               uint16_t* __restrict__ oc) {         // O_concat bf16 [4096][1024]
    __shared__ __align__(16) uint16_t Ks[2][64 * 64];   // swizzled: (t, chunk c) at t*64 + (c^(t&7))*8
    __shared__ __align__(16) uint16_t Vs[2][64 * 64];   // swizzled: (d, chunk c) likewise
    __shared__ __align__(16) uint16_t Pl[8][16][72];    // per-wave P^T strip [q16][t64+pad]

    int tid = threadIdx.x;
    int w = tid >> 6, lane = tid & 63;
    int qd = lane >> 4, ln = lane & 15;
    int lnx = ln & 7;
    int bid = blockIdx.x;
    int j = bid >> 5;                  // 0..7 pair index
    int bh = bid & 31;                 // bid%8 == bh%8 → bh→XCD L2 affinity
    int b = bh >> 4, h = bh & 15;

    const uint16_t* Q0 = qkvb + (size_t)bh * T_ * D_;
    const uint16_t* K  = Q0 + 4194304;
    const uint16_t* Vt = qkvb + (size_t)2 * 4194304 + (size_t)bh * D_ * T_;   // [64 d][2048 t]

    int qsA = j * 128 + w * 16;        // light q-group
    int qsB = (15 - j) * 128 + w * 16; // heavy q-group
    int nt  = 32 - 2 * j;              // k-tiles needed by the heavy group

    // persistent Q fragments (B-operand, n=q16, k=d)
    short8 bqA[2], bqB[2];
#pragma unroll
    for (int ks = 0; ks < 2; ks++) {
        bqA[ks] = *(const short8*)(Q0 + (size_t)(qsA + ln) * D_ + ks * 32 + qd * 8);
        bqB[ks] = *(const short8*)(Q0 + (size_t)(qsB + ln) * D_ + ks * 32 + qd * 8);
    }

    // staging: 512 threads cover 64 rows x 8 chunks of 16B, chunk XOR-swizzled
    int srow = tid >> 3;               // 0..63
    int pch = tid & 7;
    int gch = pch ^ (srow & 7);
    const uint16_t* gk = K  + (size_t)srow * D_ + gch * 8;   // K row = kt*64+srow
    const uint16_t* gv = Vt + (size_t)srow * T_ + gch * 8;   // V^T row d = srow, col = kt*64+..
    int lofs = srow * 64 + pch * 8;

    short8 pk = *(const short8*)gk;    // tile kt=0 prefetch
    short8 pv = *(const short8*)gv;

    f32x4 otA[4] = {}, otB[4] = {};    // O^T [d-tile id][q16], per strip
    float lA = 0.f, lB = 0.f;

    int c = 0;
    for (int kt = 0; kt < nt; kt++) {
        *(short8*)&Ks[c][lofs] = pk;
        *(short8*)&Vs[c][lofs] = pv;
        __syncthreads();
        if (kt + 1 < nt) {
            pk = *(const short8*)(gk + (size_t)(kt + 1) * 64 * D_);
            pv = *(const short8*)(gv + (size_t)(kt + 1) * 64);
        }
        // shared K/V fragments for both strips (A-operands)
        short8 ak[4][2], av[4][2];
#pragma unroll
        for (int ks = 0; ks < 2; ks++) {
            int p8 = ((ks * 4 + qd) ^ lnx) * 8;
#pragma unroll
            for (int it = 0; it < 4; it++) {
                ak[it][ks] = *(const short8*)&Ks[c][(it * 16 + ln) * 64 + p8];
                av[it][ks] = *(const short8*)&Vs[c][(it * 16 + ln) * 64 + p8];
            }
        }
        STRIP(qsA, bqA, otA, lA);
        STRIP(qsB, bqB, otB, lB);
        c ^= 1;
    }

    EPI(qsA, otA, lA);
    EPI(qsB, otB, lB);
}

// ---------------------------------------------------------------- GEMM2 (tile 128x64, BK=64, swizzled, 2-deep A prefetch)
__global__ __launch_bounds__(256, 3) void gemm_out(const uint16_t* __restrict__ A,   // O_concat bf16 [4096][1024]
                                                   const uint16_t* __restrict__ Bw,  // Wt bf16 [1024][1024]
                                                   float* __restrict__ out) {        // [4096][1024] fp32
    __shared__ __align__(16) uint16_t As[128 * 64];
    __shared__ __align__(16) uint16_t Bs[64 * 64];

    int tid = threadIdx.x;
    int w = tid >> 6, lane = tid & 63;
    int qd = lane >> 4, ln = lane & 15;
    int lnx = ln & 7;
    int rowBase = blockIdx.y * 128;
    int colBase = blockIdx.x * 64;
    int mw = (w >> 1) * 64, nw = (w & 1) * 32;

    int srow = tid >> 3;
    int pchunk = tid & 7;
    int gchunk = pchunk ^ (srow & 7);

    const uint16_t* ga = A  + (size_t)(rowBase + srow) * KDIM + gchunk * 8;
    const uint16_t* gb = Bw + (size_t)(colBase + srow) * KDIM + gchunk * 8;
    uint16_t* la = &As[srow * 64 + pchunk * 8];
    uint16_t* lb = &Bs[srow * 64 + pchunk * 8];

    short8 paE[4], paO[4], pb[2];
#pragma unroll
    for (int m = 0; m < 4; m++) {
        paE[m] = *(const short8*)(ga + (size_t)m * 32 * KDIM);
        paO[m] = *(const short8*)(ga + 64 + (size_t)m * 32 * KDIM);
    }
#pragma unroll
    for (int m = 0; m < 2; m++)
        pb[m] = *(const short8*)(gb + (size_t)m * 32 * KDIM);

    f32x4 acc[4][2] = {};

#define OSTEP(PAC, S)                                                            \
    {                                                                            \
        _Pragma("unroll")                                                        \
        for (int m = 0; m < 4; m++)                                              \
            *(short8*)(la + m * 32 * 64) = PAC[m];                               \
        _Pragma("unroll")                                                        \
        for (int m = 0; m < 2; m++)                                              \
            *(short8*)(lb + m * 32 * 64) = pb[m];                                \
        __syncthreads();                                                         \
        if ((S) + 1 < 16) {                                                      \
            int kb_ = ((S) + 1) * 64;                                            \
            _Pragma("unroll")                                                    \
            for (int m = 0; m < 2; m++)                                          \
                pb[m] = *(const short8*)(gb + kb_ + (size_t)m * 32 * KDIM);      \
        }                                                                        \
        if ((S) + 2 < 16) {                                                      \
            int ka_ = ((S) + 2) * 64;                                            \
            _Pragma("unroll")                                                    \
            for (int m = 0; m < 4; m++)                                          \
                PAC[m] = *(const short8*)(ga + ka_ + (size_t)m * 32 * KDIM);     \
        }                                                                        \
        _Pragma("unroll")                                                        \
        for (int ks = 0; ks < 2; ks++) {                                         \
            int p = (ks * 4 + qd) ^ lnx;                                         \
            short8 a_[4], b_[2];                                                 \
            _Pragma("unroll")                                                    \
            for (int i = 0; i < 4; i++)                                          \
                a_[i] = *(const short8*)&As[(mw + i * 16 + ln) * 64 + p * 8];    \
            _Pragma("unroll")                                                    \
            for (int j = 0; j < 2; j++)                                          \
                b_[j] = *(const short8*)&Bs[(nw + j * 16 + ln) * 64 + p * 8];    \
            _Pragma("unroll")                                                    \
            for (int i = 0; i < 4; i++)                                          \
                _Pragma("unroll")                                                \
                for (int j = 0; j < 2; j++)                                      \
                    acc[i][j] = __builtin_amdgcn_mfma_f32_16x16x32_bf16(a_[i], b_[j], acc[i][j], 0, 0, 0); \
        }                                                                        \
        __syncthreads();                                                         \
    }

    for (int sp = 0; sp < 8; sp++) {
        OSTEP(paE, 2 * sp);
        OSTEP(paO, 2 * sp + 1);
    }
#undef OSTEP

#pragma unroll
    for (int i = 0; i < 4; i++)
#pragma unroll
        for (int j = 0; j < 2; j++)
#pragma unroll
            for (int r = 0; r < 4; r++) {
                int grow = rowBase + mw + i * 16 + qd * 4 + r;
                int gcol = colBase + nw + j * 16 + ln;
                out[(size_t)grow * 1024 + gcol] = acc[i][j][r];
            }
}

// ---------------------------------------------------------------- launch
extern "C" void kernel_launch(void* const* d_in, const int* in_sizes, int n_in,
                              void* d_out, int out_size, void* d_ws, size_t ws_size,
                              hipStream_t stream) {
    const float* x  = (const float*)d_in[0];
    const float* Wa = (const float*)d_in[1];
    const float* Wp = (const float*)d_in[2];
    float* out = (float*)d_out;

    uint16_t* ws   = (uint16_t*)d_ws;
    uint16_t* xb   = ws;                       // 4096*1024
    uint16_t* Wab  = xb + 4194304;             // 3072*1024
    uint16_t* Wtb  = Wab + 3145728;            // 1024*1024
    uint16_t* qkvb = Wtb + 1048576;            // Q,K: [bh][t][d] (Q pre-scaled by log2e); V: [bh][d][t]
    uint16_t* ob   = qkvb + (size_t)3 * 4194304; // 4096*1024

    cast_all<<<7168, 256, 0, stream>>>(x, Wa, xb, Wab, 4194304 / 4, 3145728 / 4);
    cast_wp<<<1024, 256, 0, stream>>>(Wp, Wtb);
    gemm_qkv<<<dim3(24, 32), 256, 0, stream>>>(xb, Wab, qkvb);
    attn<<<256, 512, 0, stream>>>(qkvb, ob);
    gemm_out<<<dim3(16, 32), 256, 0, stream>>>(ob, Wtb, out);
}